// Round 10
// baseline (5795.107 us; speedup 1.0000x reference)
//
#include <hip/hip_runtime.h>

// ---------------------------------------------------------------------------
// Decoder: out = (tanh(x @ (s1*tern(w1-n1)) + b1)) @ (s2*tern(w2-n2)) + b2
// B=4096, D_IN=1024, D_H=16384, D_OUT=3072
//
// Round-12: gemm2 -> BK=32 (LDS 64 KB => 2 blocks/CU co-resident) +
// split-K x4 (grid 12x16x4 = 768 blocks) with r7's verified atomic
// epilogue. Mechanism: with 128 KB LDS there was exactly 1 block/CU, so
// the ~60% stall cycles per K-step (3900 cyc measured vs 516 MFMA + 875
// LDS) had nothing to overlap with. Two co-resident blocks interleave
// (m114): one block's MFMA fills the other's barrier/vmcnt stalls.
// 4-phase skeleton scaled: 1 chunk (8 KB) per half-stage, 1 load/thread,
// vmcnt 4->2 (FIFO retire schedule re-verified phase-by-phase).
// gemm1 + packers unchanged from round-9.
//
// Chunk format (8192 B = one 128(m|n) x 32(k) bf16 tile):
//   elem(s, h, lane, e) = T[m = s*32 + (lane&31)][k = h*16 + (lane>>5)*8 + e]
//   flat elem offset = s*1024 + h*512 + lane*8 + e   (s=0..3, h=0..1)
// ---------------------------------------------------------------------------

typedef __bf16 bf16x8 __attribute__((ext_vector_type(8)));
typedef float f32x16 __attribute__((ext_vector_type(16)));

#define AS1 __attribute__((address_space(1)))
#define AS3 __attribute__((address_space(3)))

__device__ __forceinline__ void gload_lds16(const void* g, void* l) {
    __builtin_amdgcn_global_load_lds((AS1 const void*)g, (AS3 void*)l, 16, 0, 0);
}

__device__ __forceinline__ unsigned short f2bf(float f) {
    union { float f; unsigned int u; } v; v.f = f;
    unsigned int u = v.u;
    unsigned int r = u + 0x7fffu + ((u >> 16) & 1u);
    return (unsigned short)(r >> 16);
}

__device__ __forceinline__ unsigned short tern_bf(float q) {
    return (q > 1.f) ? 0x3F80u : ((q < -1.f) ? 0xBF80u : 0u);
}

__device__ __forceinline__ float load_scale(const void* p) {
    int i = *(const int*)p;
    if (i >= -1000000 && i <= 1000000) return (float)i;
    union { int i; float f; } v; v.i = i; return v.f;
}

__device__ __forceinline__ float tanh_fast(float x) {
    float e = __expf(2.0f * x);
    return 1.0f - 2.0f * __builtin_amdgcn_rcpf(e + 1.0f);
}

// ---------------------------------------------------------------------------
// zero_out: out[4096*3072] fp32 = 0 (before gemm2's atomic accumulation)
// ---------------------------------------------------------------------------
__global__ __launch_bounds__(256) void zero_out_kernel(float4* __restrict__ o)
{
    size_t base = (size_t)blockIdx.x * 1024 + threadIdx.x;
#pragma unroll
    for (int i = 0; i < 4; i++)
        o[base + i * 256] = make_float4(0.f, 0.f, 0.f, 0.f);
}

// ---------------------------------------------------------------------------
// pack_x: x[4096][1024] fp32 -> chunks [mt=32][kt=32][8192B fragment-major]
// ---------------------------------------------------------------------------
__global__ __launch_bounds__(256) void pack_x_kernel(
    const float* __restrict__ x, unsigned short* __restrict__ out)
{
    const int kt = blockIdx.x, mt = blockIdx.y, tid = threadIdx.x;
    unsigned short* chunk = out + (size_t)(mt * 32 + kt) * 4096;
#pragma unroll
    for (int it = 0; it < 2; it++) {
        int g = tid + it * 256;
        int s = g >> 7, r = g & 127, h = (r >> 6) & 1, ln = r & 63;
        int m = s * 32 + (ln & 31), k = h * 16 + (ln >> 5) * 8;
        const float* src = x + (size_t)(mt * 128 + m) * 1024 + kt * 32 + k;
        float4 v0 = *(const float4*)src;
        float4 v1 = *(const float4*)(src + 4);
        unsigned int w0 = (unsigned int)f2bf(v0.x) | ((unsigned int)f2bf(v0.y) << 16);
        unsigned int w1 = (unsigned int)f2bf(v0.z) | ((unsigned int)f2bf(v0.w) << 16);
        unsigned int w2 = (unsigned int)f2bf(v1.x) | ((unsigned int)f2bf(v1.y) << 16);
        unsigned int w3 = (unsigned int)f2bf(v1.z) | ((unsigned int)f2bf(v1.w) << 16);
        uint4 o; o.x = w0; o.y = w1; o.z = w2; o.w = w3;
        *(uint4*)&chunk[(size_t)g * 8] = o;
    }
}

// ---------------------------------------------------------------------------
// quant_pack_w (LDS-free, round-9): w,n [K][N] fp32 -> tern bf16 chunks
// [N/128][K/32][8192B fragment-major]. grid: (Kt/2, N/128), block 256.
// ---------------------------------------------------------------------------
__global__ __launch_bounds__(256) void quant_pack_w(
    const float* __restrict__ w, const float* __restrict__ nz,
    const void* __restrict__ scale_ptr,
    unsigned short* __restrict__ out, int N, int Kt)
{
    const int tid = threadIdx.x, nt = blockIdx.y;
    const int c = tid >> 7, r = tid & 127, ng = r & 31, kg = r >> 5;
    const int kt = blockIdx.x * 2 + c;
    const float scale = load_scale(scale_ptr);
    const int k0 = kt * 32 + kg * 8;
    const int n0 = nt * 128 + ng * 4;

    unsigned short us[8][4];
#pragma unroll
    for (int i = 0; i < 8; i++) {
        size_t g = (size_t)(k0 + i) * N + n0;
        float4 wv = *(const float4*)(w + g);
        float4 nv = *(const float4*)(nz + g);
        us[i][0] = tern_bf(wv.x - scale * nv.x);
        us[i][1] = tern_bf(wv.y - scale * nv.y);
        us[i][2] = tern_bf(wv.z - scale * nv.z);
        us[i][3] = tern_bf(wv.w - scale * nv.w);
    }

    unsigned short* chunk = out + (size_t)(nt * Kt + kt) * 4096;
    const int nl = ng * 4;
    const int s = nl >> 5;
    const int h = kg >> 1, hi = kg & 1;
    const int base = s * 1024 + h * 512 + hi * 256 + (nl & 31) * 8;
#pragma unroll
    for (int j = 0; j < 4; j++) {
        uint4 o;
        o.x = (unsigned)us[0][j] | ((unsigned)us[1][j] << 16);
        o.y = (unsigned)us[2][j] | ((unsigned)us[3][j] << 16);
        o.z = (unsigned)us[4][j] | ((unsigned)us[5][j] << 16);
        o.w = (unsigned)us[6][j] | ((unsigned)us[7][j] << 16);
        *(uint4*)&chunk[base + j * 8] = o;
    }
}

// ---------------------------------------------------------------------------
// Shared sync macros
// ---------------------------------------------------------------------------
#define VMCNT(n) asm volatile("s_waitcnt vmcnt(" #n ")" ::: "memory")
#define BARRIER() { asm volatile("" ::: "memory"); __builtin_amdgcn_s_barrier(); asm volatile("" ::: "memory"); }

// ---- BK=64 template pieces (gemm1, round-5 verified) ----------------------
#define RD_FRAG(dst, HALF, SUB, P)                                            \
    dst[0] = *(const bf16x8*)&lds[P][HALF][(SUB)*1024 + lane*8];              \
    dst[1] = *(const bf16x8*)&lds[P][HALF][(SUB)*1024 + 512 + lane*8];        \
    dst[2] = *(const bf16x8*)&lds[P][HALF][4096 + (SUB)*1024 + lane*8];       \
    dst[3] = *(const bf16x8*)&lds[P][HALF][4096 + (SUB)*1024 + 512 + lane*8];

#define MFMA4(ci, cj, av, bv)                                                 \
    acc[ci][cj] = __builtin_amdgcn_mfma_f32_32x32x16_bf16(av[0], bv[0], acc[ci][cj], 0,0,0); \
    acc[ci][cj] = __builtin_amdgcn_mfma_f32_32x32x16_bf16(av[1], bv[1], acc[ci][cj], 0,0,0); \
    acc[ci][cj] = __builtin_amdgcn_mfma_f32_32x32x16_bf16(av[2], bv[2], acc[ci][cj], 0,0,0); \
    acc[ci][cj] = __builtin_amdgcn_mfma_f32_32x32x16_bf16(av[3], bv[3], acc[ci][cj], 0,0,0);

#define GSTEP(P, Q, T, W0, W1, DO_STAGE, LAST)                                \
  { RD_FRAG(fa0, 0, sA, P); RD_FRAG(fa1, 0, sA + 1, P);                       \
    RD_FRAG(fb0, 2, sB, P);                                                   \
    if (DO_STAGE) STAGE(Q, 0, (T) + 1);                                       \
    W0; BARRIER();                                                            \
    __builtin_amdgcn_s_setprio(1);                                            \
    MFMA4(0, 0, fa0, fb0); MFMA4(1, 0, fa1, fb0);                             \
    __builtin_amdgcn_s_setprio(0);                                            \
    BARRIER();                                                                \
    RD_FRAG(fb1, 3, sB, P);                                                   \
    if (DO_STAGE) STAGE(Q, 2, (T) + 1);                                       \
    W1; BARRIER();                                                            \
    __builtin_amdgcn_s_setprio(1);                                            \
    MFMA4(0, 1, fa0, fb1); MFMA4(1, 1, fa1, fb1);                             \
    __builtin_amdgcn_s_setprio(0);                                            \
    BARRIER();                                                                \
    RD_FRAG(fa0, 1, sA, P); RD_FRAG(fa1, 1, sA + 1, P);                       \
    if (DO_STAGE) STAGE(Q, 3, (T) + 1);                                       \
    BARRIER();                                                                \
    __builtin_amdgcn_s_setprio(1);                                            \
    MFMA4(2, 1, fa0, fb1); MFMA4(3, 1, fa1, fb1);                             \
    __builtin_amdgcn_s_setprio(0);                                            \
    BARRIER();                                                                \
    if (DO_STAGE) STAGE(Q, 1, (T) + 1);                                       \
    if (!(LAST)) { VMCNT(4); }                                                \
    BARRIER();                                                                \
    __builtin_amdgcn_s_setprio(1);                                            \
    MFMA4(2, 0, fa0, fb0); MFMA4(3, 0, fa1, fb0);                             \
    __builtin_amdgcn_s_setprio(0);                                            \
    BARRIER();                                                                \
  }

// ---- BK=32 template pieces (gemm2, round-12) ------------------------------
#define RD2(dst, HALF, SUB, P)                                                \
    dst[0] = *(const bf16x8*)&lds[P][HALF][(SUB)*1024 + lane*8];              \
    dst[1] = *(const bf16x8*)&lds[P][HALF][(SUB)*1024 + 512 + lane*8];

#define MFMA2(ci, cj, av, bv)                                                 \
    acc[ci][cj] = __builtin_amdgcn_mfma_f32_32x32x16_bf16(av[0], bv[0], acc[ci][cj], 0,0,0); \
    acc[ci][cj] = __builtin_amdgcn_mfma_f32_32x32x16_bf16(av[1], bv[1], acc[ci][cj], 0,0,0);

// Retire trace (1 load per half-stage): steady in-flight 3-4, vmcnt(2) at
// ph0/ph1/ph3 retires exactly the half needed next; final step: vmcnt(1)
// at ph0 (retires B1), vmcnt(0) at ph1 (retires A1), nothing at ph3.
#define GSTEP32(P, Q, T, W0, W1, W2, DO_STAGE)                                \
  { RD2(ga0, 0, sA, P); RD2(ga1, 0, sA + 1, P); RD2(gb0, 2, sB, P);           \
    if (DO_STAGE) STAGE(Q, 0, (T) + 1);                                       \
    W0; BARRIER();                                                            \
    __builtin_amdgcn_s_setprio(1);                                            \
    MFMA2(0, 0, ga0, gb0); MFMA2(1, 0, ga1, gb0);                             \
    __builtin_amdgcn_s_setprio(0);                                            \
    BARRIER();                                                                \
    RD2(gb1, 3, sB, P);                                                       \
    if (DO_STAGE) STAGE(Q, 2, (T) + 1);                                       \
    W1; BARRIER();                                                            \
    __builtin_amdgcn_s_setprio(1);                                            \
    MFMA2(0, 1, ga0, gb1); MFMA2(1, 1, ga1, gb1);                             \
    __builtin_amdgcn_s_setprio(0);                                            \
    BARRIER();                                                                \
    RD2(ga0, 1, sA, P); RD2(ga1, 1, sA + 1, P);                               \
    if (DO_STAGE) STAGE(Q, 3, (T) + 1);                                       \
    BARRIER();                                                                \
    __builtin_amdgcn_s_setprio(1);                                            \
    MFMA2(2, 1, ga0, gb1); MFMA2(3, 1, ga1, gb1);                             \
    __builtin_amdgcn_s_setprio(0);                                            \
    BARRIER();                                                                \
    if (DO_STAGE) STAGE(Q, 1, (T) + 1);                                       \
    W2; BARRIER();                                                            \
    __builtin_amdgcn_s_setprio(1);                                            \
    MFMA2(2, 0, ga0, gb0); MFMA2(3, 0, ga1, gb0);                             \
    __builtin_amdgcn_s_setprio(0);                                            \
    BARRIER();                                                                \
  }

// ---------------------------------------------------------------------------
// GEMM1 (256^2, swapped; round-5 verified): A = w1q (n1/k2), B = xq (batch).
// Grid (NT=16 batch, MT=64 n1) = 1024 blocks. K=1024 -> 16 steps (BK=64).
// ---------------------------------------------------------------------------
__global__ __launch_bounds__(512, 2) void gemm1_256_kernel(
    const unsigned short* __restrict__ Ap,   // w1q chunks [(n1>>7)][kt=32]
    const unsigned short* __restrict__ Bp,   // xq  chunks [(m>>7)][kt=32]
    unsigned short* __restrict__ Hq,
    const float* __restrict__ s1v, const float* __restrict__ b1v)
{
    __shared__ unsigned short lds[2][4][8192];   // 128 KiB
    const int tid = threadIdx.x;
    const int lane = tid & 63, wave = tid >> 6;
    const int NT = blockIdx.x;     // batch / 256
    const int MT = blockIdx.y;     // n1 / 256
    const int wm = ((wave >> 2) & 1) * 64;
    const int sA = wm >> 5;
    const int sB = wave & 3;

    f32x16 acc[4][2] = {};

    const unsigned short* Ab = Ap + ((size_t)(2 * MT) * 32) * 4096;
    const unsigned short* Bb = Bp + ((size_t)(2 * NT) * 32) * 4096;

    auto STAGE = [&](int q, int half, int t) {
        const unsigned short* g = (half < 2)
            ? (Ab + ((size_t)(half * 32 + 2 * t)) * 4096)
            : (Bb + ((size_t)((half - 2) * 32 + 2 * t)) * 4096);
        unsigned short* l = &lds[q][half][0];
        gload_lds16(g + tid * 8,        l + tid * 8);
        gload_lds16(g + 4096 + tid * 8, l + 4096 + tid * 8);
    };

    bf16x8 fa0[4], fa1[4], fb0[4], fb1[4];

    STAGE(0, 0, 0); STAGE(0, 2, 0); STAGE(0, 3, 0); STAGE(0, 1, 0);
    VMCNT(4);
    BARRIER();

    for (int t = 0; t < 14; t += 2) {
        GSTEP(0, 1, t,     VMCNT(4), VMCNT(4), true, false);
        GSTEP(1, 0, t + 1, VMCNT(4), VMCNT(4), true, false);
    }
    GSTEP(0, 1, 14, VMCNT(4), VMCNT(4), true,  false);
    GSTEP(1, 0, 15, VMCNT(2), VMCNT(0), false, true);

    // ---- epilogue: tanh + pack into 16-chunk LDS image, then stream out.
    const int mloc = lane & 31, hi = lane >> 5;
    unsigned int* stg32 = (unsigned int*)&lds[0][0][0];
#pragma unroll
    for (int i = 0; i < 4; i++) {
        const int kc  = (i >> 1) * 4 + sA + (i & 1);   // 0..7, disjoint per wm
        const int k2b = MT * 256 + (i >> 1) * 128 + wm + (i & 1) * 32;
#pragma unroll
        for (int j = 0; j < 2; j++) {
#pragma unroll
            for (int c = 0; c < 8; c++) {
                const int n1off = 8 * (c >> 1) + 4 * hi + 2 * (c & 1);
                const int n1g = k2b + n1off;
                float t0 = tanh_fast(s1v[n1g]     * acc[i][j][2 * c]     + b1v[n1g]);
                float t1 = tanh_fast(s1v[n1g + 1] * acc[i][j][2 * c + 1] + b1v[n1g + 1]);
                unsigned int pw = (unsigned int)f2bf(t0)
                                | ((unsigned int)f2bf(t1) << 16);
                const int a32 = (j * 8 + kc) * 2048 + sB * 512
                              + ((c >> 2) & 1) * 256 + ((c >> 1) & 1) * 128
                              + mloc * 4 + 2 * hi + (c & 1);
                stg32[a32] = pw;
            }
        }
    }
    __syncthreads();

#pragma unroll
    for (int mg = 0; mg < 2; mg++) {
        uint4* dst = (uint4*)(Hq + ((size_t)(2 * NT + mg) * 512 + MT * 8) * 4096);
        const uint4* src = (const uint4*)&lds[0][0][0];
#pragma unroll
        for (int it = 0; it < 8; it++)
            dst[it * 512 + tid] = src[mg * 4096 + it * 512 + tid];
    }
}

// ---------------------------------------------------------------------------
// GEMM2 (256^2, BK=32, split-K x4, 2 blocks/CU): out += s2[n]*acc (+b2 on
// split 0). Grid (12, 16, 4) = 768 blocks; LDS 64 KB -> 2 co-resident
// blocks per CU; one block's MFMA fills the other's barrier/vmcnt stalls.
// Split s covers K-chunks [s*128, s*128+128). NT staggered per split.
// Requires out pre-zeroed.
// ---------------------------------------------------------------------------
__global__ __launch_bounds__(512, 4) void gemm2_256_kernel(
    const unsigned short* __restrict__ Ap,   // hq  chunks [mt128][k2t=512]
    const unsigned short* __restrict__ Bp,   // w2q chunks [nt128][k2t=512]
    float* __restrict__ out,
    const float* __restrict__ s2, const float* __restrict__ b2)
{
    __shared__ unsigned short lds[2][4][4096];   // 64 KiB
    const int tid = threadIdx.x;
    const int lane = tid & 63, wave = tid >> 6;
    const int split = blockIdx.z;
    const int NT = (blockIdx.x + 3 * split) % 12;
    const int MT = blockIdx.y;
    const int TB = split * 128;                  // K-chunk base (BK=32)
    const int wm = ((wave >> 2) & 1) * 64;
    const int sA = wm >> 5;
    const int sB = wave & 3;

    f32x16 acc[4][2] = {};

    const unsigned short* Ab = Ap + ((size_t)(2 * MT) * 512) * 4096;
    const unsigned short* Bb = Bp + ((size_t)(2 * NT) * 512) * 4096;

    // stage one 8 KB chunk (= one half-tile at BK=32); 1 load per thread
    auto STAGE = [&](int q, int half, int t) {
        const unsigned short* g = (half < 2)
            ? (Ab + ((size_t)(half * 512 + TB + t)) * 4096)
            : (Bb + ((size_t)((half - 2) * 512 + TB + t)) * 4096);
        gload_lds16(g + tid * 8, &lds[q][half][tid * 8]);
    };

    bf16x8 ga0[2], ga1[2], gb0[2], gb1[2];

    // prologue: stage {A0,B0,B1,A1} of chunk 0; retire A0,B0; keep B1,A1
    STAGE(0, 0, 0); STAGE(0, 2, 0); STAGE(0, 3, 0); STAGE(0, 1, 0);
    VMCNT(2);
    BARRIER();

    for (int t = 0; t < 126; t += 2) {
        GSTEP32(0, 1, t,     VMCNT(2), VMCNT(2), VMCNT(2), true);
        GSTEP32(1, 0, t + 1, VMCNT(2), VMCNT(2), VMCNT(2), true);
    }
    GSTEP32(0, 1, 126, VMCNT(2), VMCNT(2), VMCNT(2), true);
    GSTEP32(1, 0, 127, VMCNT(1), VMCNT(0), (void)0, false);

    // epilogue: atomic accumulate partial products; bias only from split 0
    const int l31 = lane & 31;
    const int rowb = 4 * (lane >> 5);
#pragma unroll
    for (int j = 0; j < 2; j++) {
        int n = NT * 256 + j * 128 + sB * 32 + l31;
        float sc = s2[n];
        float bb = (split == 0) ? b2[n] : 0.0f;
#pragma unroll
        for (int i = 0; i < 4; i++) {
            int mbase = MT * 256 + (i >> 1) * 128 + wm + (i & 1) * 32;
#pragma unroll
            for (int reg = 0; reg < 16; reg++) {
                int m = mbase + (reg & 3) + 8 * (reg >> 2) + rowb;
                unsafeAtomicAdd(&out[(size_t)m * 3072 + n],
                                sc * acc[i][j][reg] + bb);
            }
        }
    }
}

// ---------------------------------------------------------------------------
extern "C" void kernel_launch(void* const* d_in, const int* in_sizes, int n_in,
                              void* d_out, int out_size, void* d_ws, size_t ws_size,
                              hipStream_t stream) {
    const float* x  = (const float*)d_in[0];   // [4096,1024]
    const float* w1 = (const float*)d_in[1];   // [1024,16384]
    const float* s1 = (const float*)d_in[2];   // [16384]
    const float* b1 = (const float*)d_in[3];   // [16384]
    const float* w2 = (const float*)d_in[4];   // [16384,3072]
    const float* s2 = (const float*)d_in[5];   // [3072]
    const float* b2 = (const float*)d_in[6];   // [3072]
    const float* n1 = (const float*)d_in[7];   // [1024,16384]
    const float* n2 = (const float*)d_in[8];   // [16384,3072]
    const void* scale_p = d_in[9];             // scalar
    float* out = (float*)d_out;

    // workspace layout (MiB offsets): xq 8 | w1q 32 | hq 128 | w2q 96 = 264
    if (ws_size < (264ull << 20)) return;
    unsigned char* ws = (unsigned char*)d_ws;
    unsigned short* xq  = (unsigned short*)(ws);
    unsigned short* w1q = (unsigned short*)(ws + (8ull << 20));
    unsigned short* hq  = (unsigned short*)(ws + (40ull << 20));
    unsigned short* w2q = (unsigned short*)(ws + (168ull << 20));

    // zero output (gemm2 accumulates atomically)
    zero_out_kernel<<<dim3(3072), 256, 0, stream>>>((float4*)out);

    // pack/quant
    pack_x_kernel<<<dim3(32, 32), 256, 0, stream>>>(x, xq);
    quant_pack_w<<<dim3(16, 128), 256, 0, stream>>>(w1, n1, scale_p, w1q, 16384, 32);
    quant_pack_w<<<dim3(256, 24), 256, 0, stream>>>(w2, n2, scale_p, w2q, 3072, 512);

    // GEMM1 (256^2 swapped): w1^T[16384x1024] @ x^T[1024x4096] -> hq chunks
    gemm1_256_kernel<<<dim3(16, 64), 512, 0, stream>>>(w1q, xq, hq, s1, b1);
    // GEMM2: BK=32 split-K x4, 768 blocks, 2 blocks/CU, atomic accumulate
    gemm2_256_kernel<<<dim3(12, 16, 4), 512, 0, stream>>>(hq, w2q, out, s2, b2);
}

// Round 11
// 1069.684 us; speedup vs baseline: 5.4176x; 5.4176x over previous
//
#include <hip/hip_runtime.h>

// ---------------------------------------------------------------------------
// Decoder: out = (tanh(x @ (s1*tern(w1-n1)) + b1)) @ (s2*tern(w2-n2)) + b2
// B=4096, D_IN=1024, D_H=16384, D_OUT=3072
//
// Round-13: full revert to round-5 (best verified, 1056.6us) + T1 XCD-chunked
// blockIdx swizzle on both GEMMs. Mechanism: gemm2 FETCH_SIZE = 622 MB vs
// ~224 MB ideal (working set L3-fits) -> vmcnt waits eat HBM-miss latency.
// Default dispatch round-robins XCDs so panel-sharing blocks never share an
// L2. Chunked swizzle (bijective: 192%8==0, 1024%8==0) gives each XCD a
// contiguous run: gemm2 = 2 MT-panels x all 12 NT (12-way A reuse in L2);
// gemm1 = 8 MT x 16 NT (xq near-L2-resident).
// r10 lesson (recorded): 2-blocks/CU co-residency is impossible at this
// wave tile — acc alone is 128 VGPR; launch_bounds(512,4) spilled to
// scratch (14.9 GB writes, 13x slowdown).
//
// Chunk format (8192 B = one 128(m|n) x 32(k) bf16 tile):
//   elem(s, h, lane, e) = T[m = s*32 + (lane&31)][k = h*16 + (lane>>5)*8 + e]
//   flat elem offset = s*1024 + h*512 + lane*8 + e   (s=0..3, h=0..1)
// ---------------------------------------------------------------------------

typedef __bf16 bf16x8 __attribute__((ext_vector_type(8)));
typedef float f32x16 __attribute__((ext_vector_type(16)));

#define AS1 __attribute__((address_space(1)))
#define AS3 __attribute__((address_space(3)))

__device__ __forceinline__ void gload_lds16(const void* g, void* l) {
    __builtin_amdgcn_global_load_lds((AS1 const void*)g, (AS3 void*)l, 16, 0, 0);
}

__device__ __forceinline__ unsigned short f2bf(float f) {
    union { float f; unsigned int u; } v; v.f = f;
    unsigned int u = v.u;
    unsigned int r = u + 0x7fffu + ((u >> 16) & 1u);
    return (unsigned short)(r >> 16);
}

__device__ __forceinline__ unsigned short tern_bf(float q) {
    return (q > 1.f) ? 0x3F80u : ((q < -1.f) ? 0xBF80u : 0u);
}

__device__ __forceinline__ float load_scale(const void* p) {
    int i = *(const int*)p;
    if (i >= -1000000 && i <= 1000000) return (float)i;
    union { int i; float f; } v; v.i = i; return v.f;
}

__device__ __forceinline__ float tanh_fast(float x) {
    float e = __expf(2.0f * x);
    return 1.0f - 2.0f * __builtin_amdgcn_rcpf(e + 1.0f);
}

// ---------------------------------------------------------------------------
// pack_x: x[4096][1024] fp32 -> chunks [mt=32][kt=32][8192B fragment-major]
// ---------------------------------------------------------------------------
__global__ __launch_bounds__(256) void pack_x_kernel(
    const float* __restrict__ x, unsigned short* __restrict__ out)
{
    const int kt = blockIdx.x, mt = blockIdx.y, tid = threadIdx.x;
    unsigned short* chunk = out + (size_t)(mt * 32 + kt) * 4096;
#pragma unroll
    for (int it = 0; it < 2; it++) {
        int g = tid + it * 256;
        int s = g >> 7, r = g & 127, h = (r >> 6) & 1, ln = r & 63;
        int m = s * 32 + (ln & 31), k = h * 16 + (ln >> 5) * 8;
        const float* src = x + (size_t)(mt * 128 + m) * 1024 + kt * 32 + k;
        float4 v0 = *(const float4*)src;
        float4 v1 = *(const float4*)(src + 4);
        unsigned int w0 = (unsigned int)f2bf(v0.x) | ((unsigned int)f2bf(v0.y) << 16);
        unsigned int w1 = (unsigned int)f2bf(v0.z) | ((unsigned int)f2bf(v0.w) << 16);
        unsigned int w2 = (unsigned int)f2bf(v1.x) | ((unsigned int)f2bf(v1.y) << 16);
        unsigned int w3 = (unsigned int)f2bf(v1.z) | ((unsigned int)f2bf(v1.w) << 16);
        uint4 o; o.x = w0; o.y = w1; o.z = w2; o.w = w3;
        *(uint4*)&chunk[(size_t)g * 8] = o;
    }
}

// ---------------------------------------------------------------------------
// quant_pack_w (round-5 form): w,n [K][N] fp32 -> tern bf16 chunks
// [N/128][K/32][8192B]. LDS transpose (stride 34), 16B coalesced stores.
// grid (Kt, N/128), block 256.
// ---------------------------------------------------------------------------
__global__ __launch_bounds__(256) void quant_pack_w(
    const float* __restrict__ w, const float* __restrict__ nz,
    const void* __restrict__ scale_ptr,
    unsigned short* __restrict__ out, int N, int Kt)
{
    __shared__ unsigned short lt[128 * 34];
    const int kt = blockIdx.x, nt = blockIdx.y, tid = threadIdx.x;
    const float scale = load_scale(scale_ptr);
#pragma unroll
    for (int it = 0; it < 4; it++) {
        int p = it * 1024 + tid * 4;
        int kr = p >> 7, nc = p & 127;
        size_t g = (size_t)(kt * 32 + kr) * N + nt * 128 + nc;
        float4 wv = *(const float4*)(w + g);
        float4 nv = *(const float4*)(nz + g);
        lt[(nc + 0) * 34 + kr] = tern_bf(wv.x - scale * nv.x);
        lt[(nc + 1) * 34 + kr] = tern_bf(wv.y - scale * nv.y);
        lt[(nc + 2) * 34 + kr] = tern_bf(wv.z - scale * nv.z);
        lt[(nc + 3) * 34 + kr] = tern_bf(wv.w - scale * nv.w);
    }
    __syncthreads();
    unsigned short* chunk = out + (size_t)(nt * Kt + kt) * 4096;
#pragma unroll
    for (int it = 0; it < 2; it++) {
        int g = tid + it * 256;
        int s = g >> 7, r = g & 127, h = (r >> 6) & 1, ln = r & 63;
        int n = s * 32 + (ln & 31), k = h * 16 + (ln >> 5) * 8;
        const unsigned int* p32 = (const unsigned int*)&lt[n * 34 + k];
        uint4 o; o.x = p32[0]; o.y = p32[1]; o.z = p32[2]; o.w = p32[3];
        *(uint4*)&chunk[(size_t)g * 8] = o;
    }
}

// ---------------------------------------------------------------------------
// 256x256 4-phase pipelined GEMM template (round-2/5 verified form).
// 8 waves (2 x 4): wm = ((wave>>2)&1)*64, sB = wave&3.
// Wave output: 128(rows) x 64(cols) = acc[4][2] of 32x32 tiles.
// LDS lds[dbuf2][half4][8192 u16]. Phases/K-step (BK=64):
//   ph0 A0xB0 (stage A0'); ph1 A0xB1 (stage B0'); ph2 A1xB1 (stage B1');
//   ph3 A1xB0 (stage A1', vmcnt(4)). Never drained to 0 in main loop.
// ---------------------------------------------------------------------------

#define VMCNT(n) asm volatile("s_waitcnt vmcnt(" #n ")" ::: "memory")
#define BARRIER() { asm volatile("" ::: "memory"); __builtin_amdgcn_s_barrier(); asm volatile("" ::: "memory"); }

#define RD_FRAG(dst, HALF, SUB, P)                                            \
    dst[0] = *(const bf16x8*)&lds[P][HALF][(SUB)*1024 + lane*8];              \
    dst[1] = *(const bf16x8*)&lds[P][HALF][(SUB)*1024 + 512 + lane*8];        \
    dst[2] = *(const bf16x8*)&lds[P][HALF][4096 + (SUB)*1024 + lane*8];       \
    dst[3] = *(const bf16x8*)&lds[P][HALF][4096 + (SUB)*1024 + 512 + lane*8];

#define MFMA4(ci, cj, av, bv)                                                 \
    acc[ci][cj] = __builtin_amdgcn_mfma_f32_32x32x16_bf16(av[0], bv[0], acc[ci][cj], 0,0,0); \
    acc[ci][cj] = __builtin_amdgcn_mfma_f32_32x32x16_bf16(av[1], bv[1], acc[ci][cj], 0,0,0); \
    acc[ci][cj] = __builtin_amdgcn_mfma_f32_32x32x16_bf16(av[2], bv[2], acc[ci][cj], 0,0,0); \
    acc[ci][cj] = __builtin_amdgcn_mfma_f32_32x32x16_bf16(av[3], bv[3], acc[ci][cj], 0,0,0);

#define GSTEP(P, Q, T, W0, W1, DO_STAGE, LAST)                                \
  { RD_FRAG(fa0, 0, sA, P); RD_FRAG(fa1, 0, sA + 1, P);                       \
    RD_FRAG(fb0, 2, sB, P);                                                   \
    if (DO_STAGE) STAGE(Q, 0, (T) + 1);                                       \
    W0; BARRIER();                                                            \
    __builtin_amdgcn_s_setprio(1);                                            \
    MFMA4(0, 0, fa0, fb0); MFMA4(1, 0, fa1, fb0);                             \
    __builtin_amdgcn_s_setprio(0);                                            \
    BARRIER();                                                                \
    RD_FRAG(fb1, 3, sB, P);                                                   \
    if (DO_STAGE) STAGE(Q, 2, (T) + 1);                                       \
    W1; BARRIER();                                                            \
    __builtin_amdgcn_s_setprio(1);                                            \
    MFMA4(0, 1, fa0, fb1); MFMA4(1, 1, fa1, fb1);                             \
    __builtin_amdgcn_s_setprio(0);                                            \
    BARRIER();                                                                \
    RD_FRAG(fa0, 1, sA, P); RD_FRAG(fa1, 1, sA + 1, P);                       \
    if (DO_STAGE) STAGE(Q, 3, (T) + 1);                                       \
    BARRIER();                                                                \
    __builtin_amdgcn_s_setprio(1);                                            \
    MFMA4(2, 1, fa0, fb1); MFMA4(3, 1, fa1, fb1);                             \
    __builtin_amdgcn_s_setprio(0);                                            \
    BARRIER();                                                                \
    if (DO_STAGE) STAGE(Q, 1, (T) + 1);                                       \
    if (!(LAST)) { VMCNT(4); }                                                \
    BARRIER();                                                                \
    __builtin_amdgcn_s_setprio(1);                                            \
    MFMA4(2, 0, fa0, fb0); MFMA4(3, 0, fa1, fb0);                             \
    __builtin_amdgcn_s_setprio(0);                                            \
    BARRIER();                                                                \
  }

// ---------------------------------------------------------------------------
// GEMM1 (256^2, swapped; round-5 verified): A = w1q (n1/k2), B = xq (batch).
// acc = h^T: k2 over regs, m over lanes == hq chunk layout.
// Grid 16x64 = 1024 blocks; XCD-chunked swizzle (1024%8==0, bijective):
// each XCD gets 128 consecutive wgids = 8 MT-panels x all 16 NT.
// ---------------------------------------------------------------------------
__global__ __launch_bounds__(512, 2) void gemm1_256_kernel(
    const unsigned short* __restrict__ Ap,   // w1q chunks [(n1>>7)][kt=32]
    const unsigned short* __restrict__ Bp,   // xq  chunks [(m>>7)][kt=32]
    unsigned short* __restrict__ Hq,
    const float* __restrict__ s1v, const float* __restrict__ b1v)
{
    __shared__ unsigned short lds[2][4][8192];   // 128 KiB
    const int tid = threadIdx.x;
    const int lane = tid & 63, wave = tid >> 6;
    // T1 XCD-chunked swizzle: bid -> (bid%8)*128 + bid/8
    const int bid0 = blockIdx.x + 16 * blockIdx.y;
    const int wg = (bid0 & 7) * 128 + (bid0 >> 3);
    const int NT = wg & 15;        // batch / 256
    const int MT = wg >> 4;        // n1 / 256
    const int wm = ((wave >> 2) & 1) * 64;
    const int sA = wm >> 5;
    const int sB = wave & 3;

    f32x16 acc[4][2] = {};

    const unsigned short* Ab = Ap + ((size_t)(2 * MT) * 32) * 4096;
    const unsigned short* Bb = Bp + ((size_t)(2 * NT) * 32) * 4096;

    auto STAGE = [&](int q, int half, int t) {
        const unsigned short* g = (half < 2)
            ? (Ab + ((size_t)(half * 32 + 2 * t)) * 4096)
            : (Bb + ((size_t)((half - 2) * 32 + 2 * t)) * 4096);
        unsigned short* l = &lds[q][half][0];
        gload_lds16(g + tid * 8,        l + tid * 8);
        gload_lds16(g + 4096 + tid * 8, l + 4096 + tid * 8);
    };

    bf16x8 fa0[4], fa1[4], fb0[4], fb1[4];

    STAGE(0, 0, 0); STAGE(0, 2, 0); STAGE(0, 3, 0); STAGE(0, 1, 0);
    VMCNT(4);
    BARRIER();

    for (int t = 0; t < 14; t += 2) {
        GSTEP(0, 1, t,     VMCNT(4), VMCNT(4), true, false);
        GSTEP(1, 0, t + 1, VMCNT(4), VMCNT(4), true, false);
    }
    GSTEP(0, 1, 14, VMCNT(4), VMCNT(4), true,  false);
    GSTEP(1, 0, 15, VMCNT(2), VMCNT(0), false, true);

    // ---- epilogue: tanh + pack into 16-chunk LDS image, then stream out.
    // acc[i][j]: k2 rows base = MT*256 + (i>>1)*128 + wm + (i&1)*32 (regs),
    //            m cols = NT*256 + j*128 + sB*32 + (lane&31) (lanes).
    // LDS image order: [mg = j (2)][k2 chunk kc (8)][4096 u16 chunk].
    const int mloc = lane & 31, hi = lane >> 5;
    unsigned int* stg32 = (unsigned int*)&lds[0][0][0];
#pragma unroll
    for (int i = 0; i < 4; i++) {
        const int kc  = (i >> 1) * 4 + sA + (i & 1);   // 0..7, disjoint per wm
        const int k2b = MT * 256 + (i >> 1) * 128 + wm + (i & 1) * 32;
#pragma unroll
        for (int j = 0; j < 2; j++) {
#pragma unroll
            for (int c = 0; c < 8; c++) {
                // regs 2c,2c+1 hold k2 rows n1off, n1off+1
                const int n1off = 8 * (c >> 1) + 4 * hi + 2 * (c & 1);
                const int n1g = k2b + n1off;
                float t0 = tanh_fast(s1v[n1g]     * acc[i][j][2 * c]     + b1v[n1g]);
                float t1 = tanh_fast(s1v[n1g + 1] * acc[i][j][2 * c + 1] + b1v[n1g + 1]);
                unsigned int pw = (unsigned int)f2bf(t0)
                                | ((unsigned int)f2bf(t1) << 16);
                const int a32 = (j * 8 + kc) * 2048 + sB * 512
                              + ((c >> 2) & 1) * 256 + ((c >> 1) & 1) * 128
                              + mloc * 4 + 2 * hi + (c & 1);
                stg32[a32] = pw;
            }
        }
    }
    __syncthreads();

    // stream out: per m-group, 8 contiguous chunks = 64 KB = 4096 uint4,
    // image group mg starts at mg*4096 uint4. 8 iters x 512 thr x 16 B.
#pragma unroll
    for (int mg = 0; mg < 2; mg++) {
        uint4* dst = (uint4*)(Hq + ((size_t)(2 * NT + mg) * 512 + MT * 8) * 4096);
        const uint4* src = (const uint4*)&lds[0][0][0];
#pragma unroll
        for (int it = 0; it < 8; it++)
            dst[it * 512 + tid] = src[mg * 4096 + it * 512 + tid];
    }
}

// ---------------------------------------------------------------------------
// GEMM2 (256^2, round-2 verified): out[m][n] = s2[n]*acc + b2[n].
// Grid 12x16 = 192 blocks; XCD-chunked swizzle (192%8==0, bijective):
// each XCD gets 24 consecutive wgids = 2 MT-panels x all 12 NT -> A-panel
// chunks get 12-way L2 reuse per XCD instead of 0.
// ---------------------------------------------------------------------------
__global__ __launch_bounds__(512, 2) void gemm2_256_kernel(
    const unsigned short* __restrict__ Ap,   // hq  chunks [mt128][k2t=512]
    const unsigned short* __restrict__ Bp,   // w2q chunks [nt128][k2t=512]
    float* __restrict__ out,
    const float* __restrict__ s2, const float* __restrict__ b2,
    int nstep)                                // K / 64 = 256
{
    __shared__ unsigned short lds[2][4][8192];   // 128 KiB
    const int tid = threadIdx.x;
    const int lane = tid & 63, wave = tid >> 6;
    // T1 XCD-chunked swizzle: bid -> (bid%8)*24 + bid/8
    const int bid0 = blockIdx.x + 12 * blockIdx.y;
    const int wg = (bid0 & 7) * 24 + (bid0 >> 3);
    const int NT = wg % 12;
    const int MT = wg / 12;
    const int wm = ((wave >> 2) & 1) * 64;
    const int sA = wm >> 5;
    const int sB = wave & 3;

    f32x16 acc[4][2] = {};

    const unsigned short* Ab = Ap + ((size_t)(2 * MT) * 512) * 4096;
    const unsigned short* Bb = Bp + ((size_t)(2 * NT) * 512) * 4096;

    auto STAGE = [&](int q, int half, int t) {
        const unsigned short* g = (half < 2)
            ? (Ab + ((size_t)(half * 512 + 2 * t)) * 4096)
            : (Bb + ((size_t)((half - 2) * 512 + 2 * t)) * 4096);
        unsigned short* l = &lds[q][half][0];
        gload_lds16(g + tid * 8,        l + tid * 8);
        gload_lds16(g + 4096 + tid * 8, l + 4096 + tid * 8);
    };

    bf16x8 fa0[4], fa1[4], fb0[4], fb1[4];

    STAGE(0, 0, 0); STAGE(0, 2, 0); STAGE(0, 3, 0); STAGE(0, 1, 0);
    VMCNT(4);
    BARRIER();

    for (int t = 0; t < nstep - 2; t += 2) {
        GSTEP(0, 1, t,     VMCNT(4), VMCNT(4), true, false);
        GSTEP(1, 0, t + 1, VMCNT(4), VMCNT(4), true, false);
    }
    GSTEP(0, 1, nstep - 2, VMCNT(4), VMCNT(4), true,  false);
    GSTEP(1, 0, nstep - 1, VMCNT(2), VMCNT(0), false, true);

    const int l31 = lane & 31;
    const int rowb = 4 * (lane >> 5);
#pragma unroll
    for (int j = 0; j < 2; j++) {
        int n = NT * 256 + j * 128 + sB * 32 + l31;
        float sc = s2[n], bb = b2[n];
#pragma unroll
        for (int i = 0; i < 4; i++) {
            int mbase = MT * 256 + (i >> 1) * 128 + wm + (i & 1) * 32;
#pragma unroll
            for (int reg = 0; reg < 16; reg++) {
                int m = mbase + (reg & 3) + 8 * (reg >> 2) + rowb;
                out[(size_t)m * 3072 + n] = sc * acc[i][j][reg] + bb;
            }
        }
    }
}

// ---------------------------------------------------------------------------
extern "C" void kernel_launch(void* const* d_in, const int* in_sizes, int n_in,
                              void* d_out, int out_size, void* d_ws, size_t ws_size,
                              hipStream_t stream) {
    const float* x  = (const float*)d_in[0];   // [4096,1024]
    const float* w1 = (const float*)d_in[1];   // [1024,16384]
    const float* s1 = (const float*)d_in[2];   // [16384]
    const float* b1 = (const float*)d_in[3];   // [16384]
    const float* w2 = (const float*)d_in[4];   // [16384,3072]
    const float* s2 = (const float*)d_in[5];   // [3072]
    const float* b2 = (const float*)d_in[6];   // [3072]
    const float* n1 = (const float*)d_in[7];   // [1024,16384]
    const float* n2 = (const float*)d_in[8];   // [16384,3072]
    const void* scale_p = d_in[9];             // scalar
    float* out = (float*)d_out;

    // workspace layout (MiB offsets): xq 8 | w1q 32 | hq 128 | w2q 96 = 264
    if (ws_size < (264ull << 20)) return;
    unsigned char* ws = (unsigned char*)d_ws;
    unsigned short* xq  = (unsigned short*)(ws);
    unsigned short* w1q = (unsigned short*)(ws + (8ull << 20));
    unsigned short* hq  = (unsigned short*)(ws + (40ull << 20));
    unsigned short* w2q = (unsigned short*)(ws + (168ull << 20));

    // pack/quant
    pack_x_kernel<<<dim3(32, 32), 256, 0, stream>>>(x, xq);
    quant_pack_w<<<dim3(32, 128), 256, 0, stream>>>(w1, n1, scale_p, w1q, 16384, 32);
    quant_pack_w<<<dim3(512, 24), 256, 0, stream>>>(w2, n2, scale_p, w2q, 3072, 512);

    // GEMM1 (256^2 swapped): w1^T[16384x1024] @ x^T[1024x4096] -> hq chunks
    gemm1_256_kernel<<<dim3(16, 64), 512, 0, stream>>>(w1q, xq, hq, s1, b1);
    // GEMM2: [4096x16384] @ [16384x3072] -> out fp32
    gemm2_256_kernel<<<dim3(12, 16), 512, 0, stream>>>(hq, w2q, out, s2, b2, 256);
}

// Round 12
// 1031.251 us; speedup vs baseline: 5.6195x; 1.0373x over previous
//
#include <hip/hip_runtime.h>

// ---------------------------------------------------------------------------
// Decoder: out = (tanh(x @ (s1*tern(w1-n1)) + b1)) @ (s2*tern(w2-n2)) + b2
// B=4096, D_IN=1024, D_H=16384, D_OUT=3072
//
// Round-14: round-11 base (round-5 GEMMs + T1 XCD swizzle; swizzle kept:
// FETCH 622->459 MB confirmed, dur-neutral) with ONE isolated change:
// the 4 post-MFMA barriers removed from GSTEP (8 -> 4 barriers/K-step).
// Staging order / vmcnt placement byte-identical to round-5 (round-8's
// regression came from batching stages, seen as +140 MB FETCH; this change
// keeps memory-issue timing untouched — FETCH is the control counter).
// Safety: barriers are pre-MFMA so wave skew <= 1 phase; stages target
// buffer Q, reads target P (disjoint within a step); a wave reaches step
// t+1 ph0 (first restage of P_t) only after passing t's ph3 barrier, which
// follows every wave's ph2 MFMA in program order, and each phase's MFMA
// consumes that phase's ds_reads (lgkmcnt) -> all reads of P_t complete
// before restage. gemm1 keeps an explicit __syncthreads() before its LDS
// image pass.
//
// Chunk format (8192 B = one 128(m|n) x 32(k) bf16 tile):
//   elem(s, h, lane, e) = T[m = s*32 + (lane&31)][k = h*16 + (lane>>5)*8 + e]
//   flat elem offset = s*1024 + h*512 + lane*8 + e   (s=0..3, h=0..1)
// ---------------------------------------------------------------------------

typedef __bf16 bf16x8 __attribute__((ext_vector_type(8)));
typedef float f32x16 __attribute__((ext_vector_type(16)));

#define AS1 __attribute__((address_space(1)))
#define AS3 __attribute__((address_space(3)))

__device__ __forceinline__ void gload_lds16(const void* g, void* l) {
    __builtin_amdgcn_global_load_lds((AS1 const void*)g, (AS3 void*)l, 16, 0, 0);
}

__device__ __forceinline__ unsigned short f2bf(float f) {
    union { float f; unsigned int u; } v; v.f = f;
    unsigned int u = v.u;
    unsigned int r = u + 0x7fffu + ((u >> 16) & 1u);
    return (unsigned short)(r >> 16);
}

__device__ __forceinline__ unsigned short tern_bf(float q) {
    return (q > 1.f) ? 0x3F80u : ((q < -1.f) ? 0xBF80u : 0u);
}

__device__ __forceinline__ float load_scale(const void* p) {
    int i = *(const int*)p;
    if (i >= -1000000 && i <= 1000000) return (float)i;
    union { int i; float f; } v; v.i = i; return v.f;
}

__device__ __forceinline__ float tanh_fast(float x) {
    float e = __expf(2.0f * x);
    return 1.0f - 2.0f * __builtin_amdgcn_rcpf(e + 1.0f);
}

// ---------------------------------------------------------------------------
// pack_x: x[4096][1024] fp32 -> chunks [mt=32][kt=32][8192B fragment-major]
// ---------------------------------------------------------------------------
__global__ __launch_bounds__(256) void pack_x_kernel(
    const float* __restrict__ x, unsigned short* __restrict__ out)
{
    const int kt = blockIdx.x, mt = blockIdx.y, tid = threadIdx.x;
    unsigned short* chunk = out + (size_t)(mt * 32 + kt) * 4096;
#pragma unroll
    for (int it = 0; it < 2; it++) {
        int g = tid + it * 256;
        int s = g >> 7, r = g & 127, h = (r >> 6) & 1, ln = r & 63;
        int m = s * 32 + (ln & 31), k = h * 16 + (ln >> 5) * 8;
        const float* src = x + (size_t)(mt * 128 + m) * 1024 + kt * 32 + k;
        float4 v0 = *(const float4*)src;
        float4 v1 = *(const float4*)(src + 4);
        unsigned int w0 = (unsigned int)f2bf(v0.x) | ((unsigned int)f2bf(v0.y) << 16);
        unsigned int w1 = (unsigned int)f2bf(v0.z) | ((unsigned int)f2bf(v0.w) << 16);
        unsigned int w2 = (unsigned int)f2bf(v1.x) | ((unsigned int)f2bf(v1.y) << 16);
        unsigned int w3 = (unsigned int)f2bf(v1.z) | ((unsigned int)f2bf(v1.w) << 16);
        uint4 o; o.x = w0; o.y = w1; o.z = w2; o.w = w3;
        *(uint4*)&chunk[(size_t)g * 8] = o;
    }
}

// ---------------------------------------------------------------------------
// quant_pack_w (round-5 form): w,n [K][N] fp32 -> tern bf16 chunks
// [N/128][K/32][8192B]. grid (Kt, N/128), block 256.
// ---------------------------------------------------------------------------
__global__ __launch_bounds__(256) void quant_pack_w(
    const float* __restrict__ w, const float* __restrict__ nz,
    const void* __restrict__ scale_ptr,
    unsigned short* __restrict__ out, int N, int Kt)
{
    __shared__ unsigned short lt[128 * 34];
    const int kt = blockIdx.x, nt = blockIdx.y, tid = threadIdx.x;
    const float scale = load_scale(scale_ptr);
#pragma unroll
    for (int it = 0; it < 4; it++) {
        int p = it * 1024 + tid * 4;
        int kr = p >> 7, nc = p & 127;
        size_t g = (size_t)(kt * 32 + kr) * N + nt * 128 + nc;
        float4 wv = *(const float4*)(w + g);
        float4 nv = *(const float4*)(nz + g);
        lt[(nc + 0) * 34 + kr] = tern_bf(wv.x - scale * nv.x);
        lt[(nc + 1) * 34 + kr] = tern_bf(wv.y - scale * nv.y);
        lt[(nc + 2) * 34 + kr] = tern_bf(wv.z - scale * nv.z);
        lt[(nc + 3) * 34 + kr] = tern_bf(wv.w - scale * nv.w);
    }
    __syncthreads();
    unsigned short* chunk = out + (size_t)(nt * Kt + kt) * 4096;
#pragma unroll
    for (int it = 0; it < 2; it++) {
        int g = tid + it * 256;
        int s = g >> 7, r = g & 127, h = (r >> 6) & 1, ln = r & 63;
        int n = s * 32 + (ln & 31), k = h * 16 + (ln >> 5) * 8;
        const unsigned int* p32 = (const unsigned int*)&lt[n * 34 + k];
        uint4 o; o.x = p32[0]; o.y = p32[1]; o.z = p32[2]; o.w = p32[3];
        *(uint4*)&chunk[(size_t)g * 8] = o;
    }
}

// ---------------------------------------------------------------------------
// 256x256 4-phase pipelined GEMM template, post-MFMA barriers elided.
// 8 waves (2 x 4): wm = ((wave>>2)&1)*64, sB = wave&3.
// Wave output: 128(rows) x 64(cols) = acc[4][2] of 32x32 tiles.
// LDS lds[dbuf2][half4][8192 u16]. Phases/K-step (BK=64):
//   ph0 A0xB0 (stage A0', vmcnt4); ph1 A0xB1 (stage B0', vmcnt4);
//   ph2 A1xB1 (stage B1'); ph3 A1xB0 (stage A1', vmcnt4).
// Each phase: reads+stage+wait -> barrier -> MFMA. 4 barriers/step.
// ---------------------------------------------------------------------------

#define VMCNT(n) asm volatile("s_waitcnt vmcnt(" #n ")" ::: "memory")
#define BARRIER() { asm volatile("" ::: "memory"); __builtin_amdgcn_s_barrier(); asm volatile("" ::: "memory"); }

#define RD_FRAG(dst, HALF, SUB, P)                                            \
    dst[0] = *(const bf16x8*)&lds[P][HALF][(SUB)*1024 + lane*8];              \
    dst[1] = *(const bf16x8*)&lds[P][HALF][(SUB)*1024 + 512 + lane*8];        \
    dst[2] = *(const bf16x8*)&lds[P][HALF][4096 + (SUB)*1024 + lane*8];       \
    dst[3] = *(const bf16x8*)&lds[P][HALF][4096 + (SUB)*1024 + 512 + lane*8];

#define MFMA4(ci, cj, av, bv)                                                 \
    acc[ci][cj] = __builtin_amdgcn_mfma_f32_32x32x16_bf16(av[0], bv[0], acc[ci][cj], 0,0,0); \
    acc[ci][cj] = __builtin_amdgcn_mfma_f32_32x32x16_bf16(av[1], bv[1], acc[ci][cj], 0,0,0); \
    acc[ci][cj] = __builtin_amdgcn_mfma_f32_32x32x16_bf16(av[2], bv[2], acc[ci][cj], 0,0,0); \
    acc[ci][cj] = __builtin_amdgcn_mfma_f32_32x32x16_bf16(av[3], bv[3], acc[ci][cj], 0,0,0);

#define GSTEP(P, Q, T, W0, W1, DO_STAGE, LAST)                                \
  { RD_FRAG(fa0, 0, sA, P); RD_FRAG(fa1, 0, sA + 1, P);                       \
    RD_FRAG(fb0, 2, sB, P);                                                   \
    if (DO_STAGE) STAGE(Q, 0, (T) + 1);                                       \
    W0; BARRIER();                                                            \
    __builtin_amdgcn_s_setprio(1);                                            \
    MFMA4(0, 0, fa0, fb0); MFMA4(1, 0, fa1, fb0);                             \
    __builtin_amdgcn_s_setprio(0);                                            \
    RD_FRAG(fb1, 3, sB, P);                                                   \
    if (DO_STAGE) STAGE(Q, 2, (T) + 1);                                       \
    W1; BARRIER();                                                            \
    __builtin_amdgcn_s_setprio(1);                                            \
    MFMA4(0, 1, fa0, fb1); MFMA4(1, 1, fa1, fb1);                             \
    __builtin_amdgcn_s_setprio(0);                                            \
    RD_FRAG(fa0, 1, sA, P); RD_FRAG(fa1, 1, sA + 1, P);                       \
    if (DO_STAGE) STAGE(Q, 3, (T) + 1);                                       \
    BARRIER();                                                                \
    __builtin_amdgcn_s_setprio(1);                                            \
    MFMA4(2, 1, fa0, fb1); MFMA4(3, 1, fa1, fb1);                             \
    __builtin_amdgcn_s_setprio(0);                                            \
    if (DO_STAGE) STAGE(Q, 1, (T) + 1);                                       \
    if (!(LAST)) { VMCNT(4); }                                                \
    BARRIER();                                                                \
    __builtin_amdgcn_s_setprio(1);                                            \
    MFMA4(2, 0, fa0, fb0); MFMA4(3, 0, fa1, fb0);                             \
    __builtin_amdgcn_s_setprio(0);                                            \
  }

// ---------------------------------------------------------------------------
// GEMM1 (256^2, swapped; round-5 verified mapping): A = w1q, B = xq.
// acc = h^T: k2 over regs, m over lanes == hq chunk layout.
// Grid 16x64 = 1024 blocks; XCD-chunked swizzle (bijective, 1024%8==0).
// ---------------------------------------------------------------------------
__global__ __launch_bounds__(512, 2) void gemm1_256_kernel(
    const unsigned short* __restrict__ Ap,   // w1q chunks [(n1>>7)][kt=32]
    const unsigned short* __restrict__ Bp,   // xq  chunks [(m>>7)][kt=32]
    unsigned short* __restrict__ Hq,
    const float* __restrict__ s1v, const float* __restrict__ b1v)
{
    __shared__ unsigned short lds[2][4][8192];   // 128 KiB
    const int tid = threadIdx.x;
    const int lane = tid & 63, wave = tid >> 6;
    const int bid0 = blockIdx.x + 16 * blockIdx.y;
    const int wg = (bid0 & 7) * 128 + (bid0 >> 3);
    const int NT = wg & 15;        // batch / 256
    const int MT = wg >> 4;        // n1 / 256
    const int wm = ((wave >> 2) & 1) * 64;
    const int sA = wm >> 5;
    const int sB = wave & 3;

    f32x16 acc[4][2] = {};

    const unsigned short* Ab = Ap + ((size_t)(2 * MT) * 32) * 4096;
    const unsigned short* Bb = Bp + ((size_t)(2 * NT) * 32) * 4096;

    auto STAGE = [&](int q, int half, int t) {
        const unsigned short* g = (half < 2)
            ? (Ab + ((size_t)(half * 32 + 2 * t)) * 4096)
            : (Bb + ((size_t)((half - 2) * 32 + 2 * t)) * 4096);
        unsigned short* l = &lds[q][half][0];
        gload_lds16(g + tid * 8,        l + tid * 8);
        gload_lds16(g + 4096 + tid * 8, l + 4096 + tid * 8);
    };

    bf16x8 fa0[4], fa1[4], fb0[4], fb1[4];

    STAGE(0, 0, 0); STAGE(0, 2, 0); STAGE(0, 3, 0); STAGE(0, 1, 0);
    VMCNT(4);
    BARRIER();

    for (int t = 0; t < 14; t += 2) {
        GSTEP(0, 1, t,     VMCNT(4), VMCNT(4), true, false);
        GSTEP(1, 0, t + 1, VMCNT(4), VMCNT(4), true, false);
    }
    GSTEP(0, 1, 14, VMCNT(4), VMCNT(4), true,  false);
    GSTEP(1, 0, 15, VMCNT(2), VMCNT(0), false, true);

    // all waves done with LDS reads before the image overwrite
    __syncthreads();

    // ---- epilogue: tanh + pack into 16-chunk LDS image, then stream out.
    // acc[i][j]: k2 rows base = MT*256 + (i>>1)*128 + wm + (i&1)*32 (regs),
    //            m cols = NT*256 + j*128 + sB*32 + (lane&31) (lanes).
    // LDS image order: [mg = j (2)][k2 chunk kc (8)][4096 u16 chunk].
    const int mloc = lane & 31, hi = lane >> 5;
    unsigned int* stg32 = (unsigned int*)&lds[0][0][0];
#pragma unroll
    for (int i = 0; i < 4; i++) {
        const int kc  = (i >> 1) * 4 + sA + (i & 1);   // 0..7, disjoint per wm
        const int k2b = MT * 256 + (i >> 1) * 128 + wm + (i & 1) * 32;
#pragma unroll
        for (int j = 0; j < 2; j++) {
#pragma unroll
            for (int c = 0; c < 8; c++) {
                const int n1off = 8 * (c >> 1) + 4 * hi + 2 * (c & 1);
                const int n1g = k2b + n1off;
                float t0 = tanh_fast(s1v[n1g]     * acc[i][j][2 * c]     + b1v[n1g]);
                float t1 = tanh_fast(s1v[n1g + 1] * acc[i][j][2 * c + 1] + b1v[n1g + 1]);
                unsigned int pw = (unsigned int)f2bf(t0)
                                | ((unsigned int)f2bf(t1) << 16);
                const int a32 = (j * 8 + kc) * 2048 + sB * 512
                              + ((c >> 2) & 1) * 256 + ((c >> 1) & 1) * 128
                              + mloc * 4 + 2 * hi + (c & 1);
                stg32[a32] = pw;
            }
        }
    }
    __syncthreads();

    // stream out: per m-group, 8 contiguous chunks = 64 KB = 4096 uint4,
    // image group mg starts at mg*4096 uint4. 8 iters x 512 thr x 16 B.
#pragma unroll
    for (int mg = 0; mg < 2; mg++) {
        uint4* dst = (uint4*)(Hq + ((size_t)(2 * NT + mg) * 512 + MT * 8) * 4096);
        const uint4* src = (const uint4*)&lds[0][0][0];
#pragma unroll
        for (int it = 0; it < 8; it++)
            dst[it * 512 + tid] = src[mg * 4096 + it * 512 + tid];
    }
}

// ---------------------------------------------------------------------------
// GEMM2 (256^2): out[m][n] = s2[n]*acc + b2[n].
// Grid 12x16 = 192 blocks; XCD-chunked swizzle (bijective, 192%8==0).
// ---------------------------------------------------------------------------
__global__ __launch_bounds__(512, 2) void gemm2_256_kernel(
    const unsigned short* __restrict__ Ap,   // hq  chunks [mt128][k2t=512]
    const unsigned short* __restrict__ Bp,   // w2q chunks [nt128][k2t=512]
    float* __restrict__ out,
    const float* __restrict__ s2, const float* __restrict__ b2,
    int nstep)                                // K / 64 = 256
{
    __shared__ unsigned short lds[2][4][8192];   // 128 KiB
    const int tid = threadIdx.x;
    const int lane = tid & 63, wave = tid >> 6;
    const int bid0 = blockIdx.x + 12 * blockIdx.y;
    const int wg = (bid0 & 7) * 24 + (bid0 >> 3);
    const int NT = wg % 12;
    const int MT = wg / 12;
    const int wm = ((wave >> 2) & 1) * 64;
    const int sA = wm >> 5;
    const int sB = wave & 3;

    f32x16 acc[4][2] = {};

    const unsigned short* Ab = Ap + ((size_t)(2 * MT) * 512) * 4096;
    const unsigned short* Bb = Bp + ((size_t)(2 * NT) * 512) * 4096;

    auto STAGE = [&](int q, int half, int t) {
        const unsigned short* g = (half < 2)
            ? (Ab + ((size_t)(half * 512 + 2 * t)) * 4096)
            : (Bb + ((size_t)((half - 2) * 512 + 2 * t)) * 4096);
        unsigned short* l = &lds[q][half][0];
        gload_lds16(g + tid * 8,        l + tid * 8);
        gload_lds16(g + 4096 + tid * 8, l + 4096 + tid * 8);
    };

    bf16x8 fa0[4], fa1[4], fb0[4], fb1[4];

    STAGE(0, 0, 0); STAGE(0, 2, 0); STAGE(0, 3, 0); STAGE(0, 1, 0);
    VMCNT(4);
    BARRIER();

    for (int t = 0; t < nstep - 2; t += 2) {
        GSTEP(0, 1, t,     VMCNT(4), VMCNT(4), true, false);
        GSTEP(1, 0, t + 1, VMCNT(4), VMCNT(4), true, false);
    }
    GSTEP(0, 1, nstep - 2, VMCNT(4), VMCNT(4), true,  false);
    GSTEP(1, 0, nstep - 1, VMCNT(2), VMCNT(0), false, true);

    const int l31 = lane & 31;
    const int rowb = 4 * (lane >> 5);
#pragma unroll
    for (int j = 0; j < 2; j++) {
        int n = NT * 256 + j * 128 + sB * 32 + l31;
        float sc = s2[n], bb = b2[n];
#pragma unroll
        for (int i = 0; i < 4; i++) {
            int mbase = MT * 256 + (i >> 1) * 128 + wm + (i & 1) * 32;
#pragma unroll
            for (int reg = 0; reg < 16; reg++) {
                int m = mbase + (reg & 3) + 8 * (reg >> 2) + rowb;
                out[(size_t)m * 3072 + n] = sc * acc[i][j][reg] + bb;
            }
        }
    }
}

// ---------------------------------------------------------------------------
extern "C" void kernel_launch(void* const* d_in, const int* in_sizes, int n_in,
                              void* d_out, int out_size, void* d_ws, size_t ws_size,
                              hipStream_t stream) {
    const float* x  = (const float*)d_in[0];   // [4096,1024]
    const float* w1 = (const float*)d_in[1];   // [1024,16384]
    const float* s1 = (const float*)d_in[2];   // [16384]
    const float* b1 = (const float*)d_in[3];   // [16384]
    const float* w2 = (const float*)d_in[4];   // [16384,3072]
    const float* s2 = (const float*)d_in[5];   // [3072]
    const float* b2 = (const float*)d_in[6];   // [3072]
    const float* n1 = (const float*)d_in[7];   // [1024,16384]
    const float* n2 = (const float*)d_in[8];   // [16384,3072]
    const void* scale_p = d_in[9];             // scalar
    float* out = (float*)d_out;

    // workspace layout (MiB offsets): xq 8 | w1q 32 | hq 128 | w2q 96 = 264
    if (ws_size < (264ull << 20)) return;
    unsigned char* ws = (unsigned char*)d_ws;
    unsigned short* xq  = (unsigned short*)(ws);
    unsigned short* w1q = (unsigned short*)(ws + (8ull << 20));
    unsigned short* hq  = (unsigned short*)(ws + (40ull << 20));
    unsigned short* w2q = (unsigned short*)(ws + (168ull << 20));

    // pack/quant
    pack_x_kernel<<<dim3(32, 32), 256, 0, stream>>>(x, xq);
    quant_pack_w<<<dim3(32, 128), 256, 0, stream>>>(w1, n1, scale_p, w1q, 16384, 32);
    quant_pack_w<<<dim3(512, 24), 256, 0, stream>>>(w2, n2, scale_p, w2q, 3072, 512);

    // GEMM1 (256^2 swapped): w1^T[16384x1024] @ x^T[1024x4096] -> hq chunks
    gemm1_256_kernel<<<dim3(16, 64), 512, 0, stream>>>(w1q, xq, hq, s1, b1);
    // GEMM2: [4096x16384] @ [16384x3072] -> out fp32
    gemm2_256_kernel<<<dim3(12, 16), 512, 0, stream>>>(hq, w2q, out, s2, b2, 256);
}

// Round 13
// 1028.231 us; speedup vs baseline: 5.6360x; 1.0029x over previous
//
#include <hip/hip_runtime.h>

// ---------------------------------------------------------------------------
// Decoder: out = (tanh(x @ (s1*tern(w1-n1)) + b1)) @ (s2*tern(w2-n2)) + b2
// B=4096, D_IN=1024, D_H=16384, D_OUT=3072
//
// Round-15: continue the round-12 lever (isolated barrier reduction):
// 4 -> 2 barriers per K-step. Reads moved AFTER the barrier so the
// all-waves RAW chain (wave's vmcnt -> barrier -> reader's ds_read) stays
// formally intact; stage issue points and all vmcnt(4) cadence are
// byte-identical to round-5/12 (FETCH_SIZE is the control counter; r8's
// regression came from batching stages, excluded by construction).
// FIFO trace (steady, per wave; 2 loads per stage): enter [P3,P1];
//  R1: stage Q0 -> 6; WA=vmcnt4 retires P3; BARRIER_A; read P0,P2,P3;
//      MFMA(0,0)(1,0); stage Q2 -> 6; WB=vmcnt4 retires P1; MFMA(0,1)(1,1)
//  R2: stage Q3 -> 6; BARRIER_C; read P1; MFMA(2,1)(3,1); stage Q1 -> 8;
//      WC=vmcnt4 retires Q0,Q2 -> exit [Q3,Q1]  (invariant restored)
// RAW: P0,P2 retired at prev WC (barrier A after); P3 at WA (pre-A);
//      P1 at WB (pre-C). WAR: every half's reads are lgkm-consumed by an
//      MFMA before the barrier that precedes its restage. Last step:
//      WA=vmcnt(2), WB=vmcnt(0), no stages. Prologue = 4 STAGEs only.
//
// Chunk format (8192 B = one 128(m|n) x 32(k) bf16 tile):
//   elem(s, h, lane, e) = T[m = s*32 + (lane&31)][k = h*16 + (lane>>5)*8 + e]
//   flat elem offset = s*1024 + h*512 + lane*8 + e   (s=0..3, h=0..1)
// ---------------------------------------------------------------------------

typedef __bf16 bf16x8 __attribute__((ext_vector_type(8)));
typedef float f32x16 __attribute__((ext_vector_type(16)));

#define AS1 __attribute__((address_space(1)))
#define AS3 __attribute__((address_space(3)))

__device__ __forceinline__ void gload_lds16(const void* g, void* l) {
    __builtin_amdgcn_global_load_lds((AS1 const void*)g, (AS3 void*)l, 16, 0, 0);
}

__device__ __forceinline__ unsigned short f2bf(float f) {
    union { float f; unsigned int u; } v; v.f = f;
    unsigned int u = v.u;
    unsigned int r = u + 0x7fffu + ((u >> 16) & 1u);
    return (unsigned short)(r >> 16);
}

__device__ __forceinline__ unsigned short tern_bf(float q) {
    return (q > 1.f) ? 0x3F80u : ((q < -1.f) ? 0xBF80u : 0u);
}

__device__ __forceinline__ float load_scale(const void* p) {
    int i = *(const int*)p;
    if (i >= -1000000 && i <= 1000000) return (float)i;
    union { int i; float f; } v; v.i = i; return v.f;
}

__device__ __forceinline__ float tanh_fast(float x) {
    float e = __expf(2.0f * x);
    return 1.0f - 2.0f * __builtin_amdgcn_rcpf(e + 1.0f);
}

// ---------------------------------------------------------------------------
// pack_x: x[4096][1024] fp32 -> chunks [mt=32][kt=32][8192B fragment-major]
// ---------------------------------------------------------------------------
__global__ __launch_bounds__(256) void pack_x_kernel(
    const float* __restrict__ x, unsigned short* __restrict__ out)
{
    const int kt = blockIdx.x, mt = blockIdx.y, tid = threadIdx.x;
    unsigned short* chunk = out + (size_t)(mt * 32 + kt) * 4096;
#pragma unroll
    for (int it = 0; it < 2; it++) {
        int g = tid + it * 256;
        int s = g >> 7, r = g & 127, h = (r >> 6) & 1, ln = r & 63;
        int m = s * 32 + (ln & 31), k = h * 16 + (ln >> 5) * 8;
        const float* src = x + (size_t)(mt * 128 + m) * 1024 + kt * 32 + k;
        float4 v0 = *(const float4*)src;
        float4 v1 = *(const float4*)(src + 4);
        unsigned int w0 = (unsigned int)f2bf(v0.x) | ((unsigned int)f2bf(v0.y) << 16);
        unsigned int w1 = (unsigned int)f2bf(v0.z) | ((unsigned int)f2bf(v0.w) << 16);
        unsigned int w2 = (unsigned int)f2bf(v1.x) | ((unsigned int)f2bf(v1.y) << 16);
        unsigned int w3 = (unsigned int)f2bf(v1.z) | ((unsigned int)f2bf(v1.w) << 16);
        uint4 o; o.x = w0; o.y = w1; o.z = w2; o.w = w3;
        *(uint4*)&chunk[(size_t)g * 8] = o;
    }
}

// ---------------------------------------------------------------------------
// quant_pack_w (round-5 form): w,n [K][N] fp32 -> tern bf16 chunks
// [N/128][K/32][8192B]. grid (Kt, N/128), block 256.
// ---------------------------------------------------------------------------
__global__ __launch_bounds__(256) void quant_pack_w(
    const float* __restrict__ w, const float* __restrict__ nz,
    const void* __restrict__ scale_ptr,
    unsigned short* __restrict__ out, int N, int Kt)
{
    __shared__ unsigned short lt[128 * 34];
    const int kt = blockIdx.x, nt = blockIdx.y, tid = threadIdx.x;
    const float scale = load_scale(scale_ptr);
#pragma unroll
    for (int it = 0; it < 4; it++) {
        int p = it * 1024 + tid * 4;
        int kr = p >> 7, nc = p & 127;
        size_t g = (size_t)(kt * 32 + kr) * N + nt * 128 + nc;
        float4 wv = *(const float4*)(w + g);
        float4 nv = *(const float4*)(nz + g);
        lt[(nc + 0) * 34 + kr] = tern_bf(wv.x - scale * nv.x);
        lt[(nc + 1) * 34 + kr] = tern_bf(wv.y - scale * nv.y);
        lt[(nc + 2) * 34 + kr] = tern_bf(wv.z - scale * nv.z);
        lt[(nc + 3) * 34 + kr] = tern_bf(wv.w - scale * nv.w);
    }
    __syncthreads();
    unsigned short* chunk = out + (size_t)(nt * Kt + kt) * 4096;
#pragma unroll
    for (int it = 0; it < 2; it++) {
        int g = tid + it * 256;
        int s = g >> 7, r = g & 127, h = (r >> 6) & 1, ln = r & 63;
        int n = s * 32 + (ln & 31), k = h * 16 + (ln >> 5) * 8;
        const unsigned int* p32 = (const unsigned int*)&lt[n * 34 + k];
        uint4 o; o.x = p32[0]; o.y = p32[1]; o.z = p32[2]; o.w = p32[3];
        *(uint4*)&chunk[(size_t)g * 8] = o;
    }
}

// ---------------------------------------------------------------------------
// 256x256 pipelined GEMM template, 2 barriers / K-step (round-15).
// 8 waves (2 x 4): wm = ((wave>>2)&1)*64, sB = wave&3.
// Wave output: 128(rows) x 64(cols) = acc[4][2] of 32x32 tiles.
// LDS lds[dbuf2][half4][8192 u16]: 0=A rows0-127, 1=A rows128-255,
// 2=B cols0-127, 3=B cols128-255.
// ---------------------------------------------------------------------------

#define VMCNT(n) asm volatile("s_waitcnt vmcnt(" #n ")" ::: "memory")
#define BARRIER() { asm volatile("" ::: "memory"); __builtin_amdgcn_s_barrier(); asm volatile("" ::: "memory"); }

#define RD_FRAG(dst, HALF, SUB, P)                                            \
    dst[0] = *(const bf16x8*)&lds[P][HALF][(SUB)*1024 + lane*8];              \
    dst[1] = *(const bf16x8*)&lds[P][HALF][(SUB)*1024 + 512 + lane*8];        \
    dst[2] = *(const bf16x8*)&lds[P][HALF][4096 + (SUB)*1024 + lane*8];       \
    dst[3] = *(const bf16x8*)&lds[P][HALF][4096 + (SUB)*1024 + 512 + lane*8];

#define MFMA4(ci, cj, av, bv)                                                 \
    acc[ci][cj] = __builtin_amdgcn_mfma_f32_32x32x16_bf16(av[0], bv[0], acc[ci][cj], 0,0,0); \
    acc[ci][cj] = __builtin_amdgcn_mfma_f32_32x32x16_bf16(av[1], bv[1], acc[ci][cj], 0,0,0); \
    acc[ci][cj] = __builtin_amdgcn_mfma_f32_32x32x16_bf16(av[2], bv[2], acc[ci][cj], 0,0,0); \
    acc[ci][cj] = __builtin_amdgcn_mfma_f32_32x32x16_bf16(av[3], bv[3], acc[ci][cj], 0,0,0);

// WA/WB/WC: vmcnt(4)/vmcnt(4)/vmcnt(4) normally; vmcnt(2)/vmcnt(0)/none on
// the last step. Stage cadence (Q0,Q2,Q3,Q1) identical to round-5/12.
#define GSTEP(P, Q, T, WA, WB, WC, DO_STAGE)                                  \
  { /* ---- region 1 ---- */                                                  \
    if (DO_STAGE) STAGE(Q, 0, (T) + 1);                                       \
    WA; BARRIER();                                                            \
    RD_FRAG(fa0, 0, sA, P); RD_FRAG(fa1, 0, sA + 1, P);                       \
    RD_FRAG(fb0, 2, sB, P); RD_FRAG(fb1, 3, sB, P);                           \
    __builtin_amdgcn_s_setprio(1);                                            \
    MFMA4(0, 0, fa0, fb0); MFMA4(1, 0, fa1, fb0);                             \
    __builtin_amdgcn_s_setprio(0);                                            \
    if (DO_STAGE) STAGE(Q, 2, (T) + 1);                                       \
    WB;                                                                       \
    __builtin_amdgcn_s_setprio(1);                                            \
    MFMA4(0, 1, fa0, fb1); MFMA4(1, 1, fa1, fb1);                             \
    __builtin_amdgcn_s_setprio(0);                                            \
    /* ---- region 2 ---- */                                                  \
    if (DO_STAGE) STAGE(Q, 3, (T) + 1);                                       \
    BARRIER();                                                                \
    RD_FRAG(fa0, 1, sA, P); RD_FRAG(fa1, 1, sA + 1, P);                       \
    __builtin_amdgcn_s_setprio(1);                                            \
    MFMA4(2, 1, fa0, fb1); MFMA4(3, 1, fa1, fb1);                             \
    __builtin_amdgcn_s_setprio(0);                                            \
    if (DO_STAGE) STAGE(Q, 1, (T) + 1);                                       \
    WC;                                                                       \
    __builtin_amdgcn_s_setprio(1);                                            \
    MFMA4(2, 0, fa0, fb0); MFMA4(3, 0, fa1, fb0);                             \
    __builtin_amdgcn_s_setprio(0);                                            \
  }

#define NOWAIT ((void)0)

// ---------------------------------------------------------------------------
// GEMM1 (256^2, swapped; round-5 verified mapping): A = w1q, B = xq.
// acc = h^T: k2 over regs, m over lanes == hq chunk layout.
// Grid 16x64 = 1024 blocks; XCD-chunked swizzle (bijective, 1024%8==0).
// ---------------------------------------------------------------------------
__global__ __launch_bounds__(512, 2) void gemm1_256_kernel(
    const unsigned short* __restrict__ Ap,   // w1q chunks [(n1>>7)][kt=32]
    const unsigned short* __restrict__ Bp,   // xq  chunks [(m>>7)][kt=32]
    unsigned short* __restrict__ Hq,
    const float* __restrict__ s1v, const float* __restrict__ b1v)
{
    __shared__ unsigned short lds[2][4][8192];   // 128 KiB
    const int tid = threadIdx.x;
    const int lane = tid & 63, wave = tid >> 6;
    const int bid0 = blockIdx.x + 16 * blockIdx.y;
    const int wg = (bid0 & 7) * 128 + (bid0 >> 3);
    const int NT = wg & 15;        // batch / 256
    const int MT = wg >> 4;        // n1 / 256
    const int wm = ((wave >> 2) & 1) * 64;
    const int sA = wm >> 5;
    const int sB = wave & 3;

    f32x16 acc[4][2] = {};

    const unsigned short* Ab = Ap + ((size_t)(2 * MT) * 32) * 4096;
    const unsigned short* Bb = Bp + ((size_t)(2 * NT) * 32) * 4096;

    auto STAGE = [&](int q, int half, int t) {
        const unsigned short* g = (half < 2)
            ? (Ab + ((size_t)(half * 32 + 2 * t)) * 4096)
            : (Bb + ((size_t)((half - 2) * 32 + 2 * t)) * 4096);
        unsigned short* l = &lds[q][half][0];
        gload_lds16(g + tid * 8,        l + tid * 8);
        gload_lds16(g + 4096 + tid * 8, l + 4096 + tid * 8);
    };

    bf16x8 fa0[4], fa1[4], fb0[4], fb1[4];

    // prologue: just stage step-0's 4 halves; first GSTEP supplies vmcnt+barrier
    STAGE(0, 0, 0); STAGE(0, 2, 0); STAGE(0, 3, 0); STAGE(0, 1, 0);

    for (int t = 0; t < 14; t += 2) {
        GSTEP(0, 1, t,     VMCNT(4), VMCNT(4), VMCNT(4), true);
        GSTEP(1, 0, t + 1, VMCNT(4), VMCNT(4), VMCNT(4), true);
    }
    GSTEP(0, 1, 14, VMCNT(4), VMCNT(4), VMCNT(4), true);
    GSTEP(1, 0, 15, VMCNT(2), VMCNT(0), NOWAIT,  false);

    // all waves done with LDS reads before the image overwrite
    __syncthreads();

    // ---- epilogue: tanh + pack into 16-chunk LDS image, then stream out.
    // acc[i][j]: k2 rows base = MT*256 + (i>>1)*128 + wm + (i&1)*32 (regs),
    //            m cols = NT*256 + j*128 + sB*32 + (lane&31) (lanes).
    // LDS image order: [mg = j (2)][k2 chunk kc (8)][4096 u16 chunk].
    const int mloc = lane & 31, hi = lane >> 5;
    unsigned int* stg32 = (unsigned int*)&lds[0][0][0];
#pragma unroll
    for (int i = 0; i < 4; i++) {
        const int kc  = (i >> 1) * 4 + sA + (i & 1);   // 0..7, disjoint per wm
        const int k2b = MT * 256 + (i >> 1) * 128 + wm + (i & 1) * 32;
#pragma unroll
        for (int j = 0; j < 2; j++) {
#pragma unroll
            for (int c = 0; c < 8; c++) {
                const int n1off = 8 * (c >> 1) + 4 * hi + 2 * (c & 1);
                const int n1g = k2b + n1off;
                float t0 = tanh_fast(s1v[n1g]     * acc[i][j][2 * c]     + b1v[n1g]);
                float t1 = tanh_fast(s1v[n1g + 1] * acc[i][j][2 * c + 1] + b1v[n1g + 1]);
                unsigned int pw = (unsigned int)f2bf(t0)
                                | ((unsigned int)f2bf(t1) << 16);
                const int a32 = (j * 8 + kc) * 2048 + sB * 512
                              + ((c >> 2) & 1) * 256 + ((c >> 1) & 1) * 128
                              + mloc * 4 + 2 * hi + (c & 1);
                stg32[a32] = pw;
            }
        }
    }
    __syncthreads();

    // stream out: per m-group, 8 contiguous chunks = 64 KB = 4096 uint4,
    // image group mg starts at mg*4096 uint4. 8 iters x 512 thr x 16 B.
#pragma unroll
    for (int mg = 0; mg < 2; mg++) {
        uint4* dst = (uint4*)(Hq + ((size_t)(2 * NT + mg) * 512 + MT * 8) * 4096);
        const uint4* src = (const uint4*)&lds[0][0][0];
#pragma unroll
        for (int it = 0; it < 8; it++)
            dst[it * 512 + tid] = src[mg * 4096 + it * 512 + tid];
    }
}

// ---------------------------------------------------------------------------
// GEMM2 (256^2): out[m][n] = s2[n]*acc + b2[n].
// Grid 12x16 = 192 blocks; XCD-chunked swizzle (bijective, 192%8==0).
// ---------------------------------------------------------------------------
__global__ __launch_bounds__(512, 2) void gemm2_256_kernel(
    const unsigned short* __restrict__ Ap,   // hq  chunks [mt128][k2t=512]
    const unsigned short* __restrict__ Bp,   // w2q chunks [nt128][k2t=512]
    float* __restrict__ out,
    const float* __restrict__ s2, const float* __restrict__ b2,
    int nstep)                                // K / 64 = 256
{
    __shared__ unsigned short lds[2][4][8192];   // 128 KiB
    const int tid = threadIdx.x;
    const int lane = tid & 63, wave = tid >> 6;
    const int bid0 = blockIdx.x + 12 * blockIdx.y;
    const int wg = (bid0 & 7) * 24 + (bid0 >> 3);
    const int NT = wg % 12;
    const int MT = wg / 12;
    const int wm = ((wave >> 2) & 1) * 64;
    const int sA = wm >> 5;
    const int sB = wave & 3;

    f32x16 acc[4][2] = {};

    const unsigned short* Ab = Ap + ((size_t)(2 * MT) * 512) * 4096;
    const unsigned short* Bb = Bp + ((size_t)(2 * NT) * 512) * 4096;

    auto STAGE = [&](int q, int half, int t) {
        const unsigned short* g = (half < 2)
            ? (Ab + ((size_t)(half * 512 + 2 * t)) * 4096)
            : (Bb + ((size_t)((half - 2) * 512 + 2 * t)) * 4096);
        unsigned short* l = &lds[q][half][0];
        gload_lds16(g + tid * 8,        l + tid * 8);
        gload_lds16(g + 4096 + tid * 8, l + 4096 + tid * 8);
    };

    bf16x8 fa0[4], fa1[4], fb0[4], fb1[4];

    // prologue: just stage step-0's 4 halves
    STAGE(0, 0, 0); STAGE(0, 2, 0); STAGE(0, 3, 0); STAGE(0, 1, 0);

    for (int t = 0; t < nstep - 2; t += 2) {
        GSTEP(0, 1, t,     VMCNT(4), VMCNT(4), VMCNT(4), true);
        GSTEP(1, 0, t + 1, VMCNT(4), VMCNT(4), VMCNT(4), true);
    }
    GSTEP(0, 1, nstep - 2, VMCNT(4), VMCNT(4), VMCNT(4), true);
    GSTEP(1, 0, nstep - 1, VMCNT(2), VMCNT(0), NOWAIT,  false);

    const int l31 = lane & 31;
    const int rowb = 4 * (lane >> 5);
#pragma unroll
    for (int j = 0; j < 2; j++) {
        int n = NT * 256 + j * 128 + sB * 32 + l31;
        float sc = s2[n], bb = b2[n];
#pragma unroll
        for (int i = 0; i < 4; i++) {
            int mbase = MT * 256 + (i >> 1) * 128 + wm + (i & 1) * 32;
#pragma unroll
            for (int reg = 0; reg < 16; reg++) {
                int m = mbase + (reg & 3) + 8 * (reg >> 2) + rowb;
                out[(size_t)m * 3072 + n] = sc * acc[i][j][reg] + bb;
            }
        }
    }
}

// ---------------------------------------------------------------------------
extern "C" void kernel_launch(void* const* d_in, const int* in_sizes, int n_in,
                              void* d_out, int out_size, void* d_ws, size_t ws_size,
                              hipStream_t stream) {
    const float* x  = (const float*)d_in[0];   // [4096,1024]
    const float* w1 = (const float*)d_in[1];   // [1024,16384]
    const float* s1 = (const float*)d_in[2];   // [16384]
    const float* b1 = (const float*)d_in[3];   // [16384]
    const float* w2 = (const float*)d_in[4];   // [16384,3072]
    const float* s2 = (const float*)d_in[5];   // [3072]
    const float* b2 = (const float*)d_in[6];   // [3072]
    const float* n1 = (const float*)d_in[7];   // [1024,16384]
    const float* n2 = (const float*)d_in[8];   // [16384,3072]
    const void* scale_p = d_in[9];             // scalar
    float* out = (float*)d_out;

    // workspace layout (MiB offsets): xq 8 | w1q 32 | hq 128 | w2q 96 = 264
    if (ws_size < (264ull << 20)) return;
    unsigned char* ws = (unsigned char*)d_ws;
    unsigned short* xq  = (unsigned short*)(ws);
    unsigned short* w1q = (unsigned short*)(ws + (8ull << 20));
    unsigned short* hq  = (unsigned short*)(ws + (40ull << 20));
    unsigned short* w2q = (unsigned short*)(ws + (168ull << 20));

    // pack/quant
    pack_x_kernel<<<dim3(32, 32), 256, 0, stream>>>(x, xq);
    quant_pack_w<<<dim3(32, 128), 256, 0, stream>>>(w1, n1, scale_p, w1q, 16384, 32);
    quant_pack_w<<<dim3(512, 24), 256, 0, stream>>>(w2, n2, scale_p, w2q, 3072, 512);

    // GEMM1 (256^2 swapped): w1^T[16384x1024] @ x^T[1024x4096] -> hq chunks
    gemm1_256_kernel<<<dim3(16, 64), 512, 0, stream>>>(w1q, xq, hq, s1, b1);
    // GEMM2: [4096x16384] @ [16384x3072] -> out fp32
    gemm2_256_kernel<<<dim3(12, 16), 512, 0, stream>>>(hq, w2q, out, s2, b2, 256);
}